// Round 6
// baseline (157.020 us; speedup 1.0000x reference)
//
#include <hip/hip_runtime.h>
#include <cmath>

#define DIM      128
#define NELEMS   8388608
#define BAND_INT 12288   // key band >= 7.3e-4 dot units; unchanged from r4/r5 (proven)

typedef __attribute__((ext_vector_type(8))) short  short8;
typedef __attribute__((ext_vector_type(4))) float  f32x4;

// ws layout (bytes):
//   0      : float Bsq[1024]        (4096)
//   4096   : int   counts[1024]     (4096)
//   8192   : double sse             (8)
//   16384  : ushort Ehi[131072]     (262144)   -> end 278528 (<= proven 540672)

__device__ inline unsigned short f2bf(float x) {
    unsigned u = __float_as_uint(x);
    unsigned r = u + 0x7FFFu + ((u >> 16) & 1u);   // RNE; inputs finite
    return (unsigned short)(r >> 16);
}

// ---- prep: E -> bf16-hi frags [ct64][kt4][lane64][j8] + Bsq (bit-identical tree) + zero ----
__global__ __launch_bounds__(256) void vq_prep_kernel(
        const float* __restrict__ e, unsigned short* __restrict__ Ehi,
        float* __restrict__ Bsq, int* __restrict__ counts, double* __restrict__ sse) {
    const int tid = threadIdx.x;
    {
        const int t  = blockIdx.x * 256 + tid;   // 0..16383
        const int c  = t >> 4;
        const int gs = t & 15;
        const int kt = gs >> 2, qd = gs & 3;
        const int d0 = gs * 8;
        const float4 v0 = *(const float4*)(e + c * DIM + d0);
        const float4 v1 = *(const float4*)(e + c * DIM + d0 + 4);
        float f[8] = {v0.x, v0.y, v0.z, v0.w, v1.x, v1.y, v1.z, v1.w};
        unsigned short h[8];
        #pragma unroll
        for (int j = 0; j < 8; ++j) h[j] = f2bf(f[j]);
        const int ct = c >> 4, n = c & 15;
        uint4 ph;
        ph.x = h[0] | (h[1] << 16); ph.y = h[2] | (h[3] << 16);
        ph.z = h[4] | (h[5] << 16); ph.w = h[6] | (h[7] << 16);
        *(uint4*)&Ehi[(((ct * 4 + kt) * 64 + qd * 16 + n) * 8)] = ph;
    }
    // Bsq: per-row math bit-identical to round-1 rowsq (float4 squares + 32-lane xor tree)
    {
        const int lane = tid & 31;
        #pragma unroll
        for (int r2 = 0; r2 < 2; ++r2) {
            const int row = blockIdx.x * 16 + (tid >> 5) * 2 + r2;
            const float4 xv = *(const float4*)(e + (size_t)row * DIM + lane * 4);
            float s = xv.x * xv.x + xv.y * xv.y + xv.z * xv.z + xv.w * xv.w;
            #pragma unroll
            for (int off = 16; off > 0; off >>= 1) s += __shfl_xor(s, off);
            if (lane == 0) Bsq[row] = s;
        }
    }
    if (blockIdx.x == 0) {
        ((int4*)counts)[tid] = make_int4(0, 0, 0, 0);
        if (tid == 0) *sse = 0.0;
    }
}

#define LOADPAIR(BUF, P)                                                        \
    do {                                                                        \
        const unsigned short* _bp = EhiH + (size_t)(P) * 4096;                  \
        _Pragma("unroll")                                                       \
        for (int _c = 0; _c < 2; ++_c)                                          \
            _Pragma("unroll")                                                   \
            for (int _kt = 0; _kt < 4; ++_kt)                                   \
                BUF[_c][_kt] = *(const short8*)&_bp[((_c * 4 + _kt) * 64 + lane) * 8]; \
    } while (0)

#define COMPUTEPAIR(BUF, P)                                                     \
    do {                                                                        \
        _Pragma("unroll")                                                       \
        for (int _c = 0; _c < 2; ++_c) {                                        \
            const int _ct = ctbase + 2 * (P) + _c;                              \
            f32x4 _a0 = cinit, _a1 = cinit;                                     \
            _Pragma("unroll")                                                   \
            for (int _kt = 0; _kt < 4; ++_kt) {                                 \
                _a0 = __builtin_amdgcn_mfma_f32_16x16x32_bf16(Af[0][_kt], BUF[_c][_kt], _a0, 0, 0, 0); \
                _a1 = __builtin_amdgcn_mfma_f32_16x16x32_bf16(Af[1][_kt], BUF[_c][_kt], _a1, 0, 0, 0); \
            }                                                                   \
            _Pragma("unroll")                                                   \
            for (int _r = 0; _r < 4; ++_r) {                                    \
                const int _k0 = (__float_as_int(_a0[_r]) & (int)0xFFFFFFC0) | _ct; \
                const int _t0 = min(K1[_r], _k0);                               \
                K1[_r] = max(K1[_r], _k0);                                      \
                K2[_r] = max(K2[_r], _t0);                                      \
                const int _k1 = (__float_as_int(_a1[_r]) & (int)0xFFFFFFC0) | _ct; \
                const int _t1 = min(K1[4 + _r], _k1);                           \
                K1[4 + _r] = max(K1[4 + _r], _k1);                              \
                K2[4 + _r] = max(K2[4 + _r], _t1);                              \
            }                                                                   \
        }                                                                       \
    } while (0)

// ---- main: barrier-free bf16 MFMA scan + exact verify + fused epilogue ----
// 512 blocks x 512 thr (8 waves); block = 128 rows x 1024 codes.
// Wave w: rows 32*(w&3)..+31 (2 rti), code-tiles [32*(w>>2), 32*(w>>2)+32).
__global__ __launch_bounds__(512) void vq_main_kernel(
        const float* __restrict__ x, const float* __restrict__ emb,
        const unsigned short* __restrict__ Ehi, const float* __restrict__ Bsq,
        int* __restrict__ counts, double* __restrict__ sse,
        float* __restrict__ out) {
    __shared__ unsigned short Xs[16384];   // 32 KB: A-hi frags [rg8][kt4][lane64][j8]; reused as sc
    __shared__ float sAsq[128];
    __shared__ int   sidx[128];
    __shared__ float pblk[2];

    const int tid  = threadIdx.x;
    const int wave = tid >> 6;
    const int lane = tid & 63;
    const int n    = lane & 15;
    const int quad = lane >> 4;
    const int wg   = wave & 3;        // row-group selector
    const int half = wave >> 2;       // code half: cts [32*half, 32*half+32)
    const int ctbase = half * 32;
    const int row0 = blockIdx.x * 128;

    // ---------- phase 0: stage A-hi frags + bit-exact Asq (round-1 tree) ----------
    {
        const int rl = tid >> 3, tq = tid & 7;   // rl 0..63
        const int dbase = tq * 16;
        #pragma unroll
        for (int w = 0; w < 2; ++w) {
            const int r  = 64 * w + rl;
            const int rg = r >> 4, m = r & 15;
            const float* xp = x + (size_t)(row0 + r) * DIM + dbase;
            float p[4];
            #pragma unroll
            for (int q = 0; q < 4; ++q) {
                const float4 v = *(const float4*)(xp + 4 * q);
                p[q] = v.x * v.x + v.y * v.y + v.z * v.z + v.w * v.w;
                const int dd = dbase + 4 * q;
                const int kt = dd >> 5, qd = (dd >> 3) & 3, j = dd & 7;
                unsigned short h0 = f2bf(v.x), h1 = f2bf(v.y), h2 = f2bf(v.z), h3 = f2bf(v.w);
                uint2 ph;
                ph.x = h0 | (h1 << 16); ph.y = h2 | (h3 << 16);
                *(uint2*)&Xs[(((rg * 4 + kt) * 64 + qd * 16 + m) * 8) + j] = ph;
            }
            // xor-tree: levels 16,8,4 cross-thread (tq bits), 2,1 intra — bit-exact vs round 1
            #pragma unroll
            for (int q = 0; q < 4; ++q) p[q] += __shfl_xor(p[q], 4);
            #pragma unroll
            for (int q = 0; q < 4; ++q) p[q] += __shfl_xor(p[q], 2);
            #pragma unroll
            for (int q = 0; q < 4; ++q) p[q] += __shfl_xor(p[q], 1);
            const float s = (p[0] + p[2]) + (p[1] + p[3]);
            if (tq == 0) sAsq[r] = s;
        }
    }
    __syncthreads();

    short8 Af[2][4];
    #pragma unroll
    for (int rti = 0; rti < 2; ++rti)
        #pragma unroll
        for (int kt = 0; kt < 4; ++kt)
            Af[rti][kt] = *(const short8*)&Xs[(((wg * 2 + rti) * 4 + kt) * 64 + lane) * 8];
    __syncthreads();   // all frag reads done before Xs is reused as scratch

    // ---------- phase 1: barrier-free scan over this wave's 16 ct-pairs ----------
    int K1[8], K2[8];
    #pragma unroll
    for (int i = 0; i < 8; ++i) { K1[i] = (int)0x80000000; K2[i] = (int)0x80000000; }

    const f32x4 cinit = {1.0f, 1.0f, 1.0f, 1.0f};   // +1.0 bias -> positive, int-monotone keys
    const unsigned short* EhiH = Ehi + (size_t)half * 65536;   // 16 pairs x 4096 shorts

    short8 BfA[2][4], BfB[2][4];
    LOADPAIR(BfA, 0);
    for (int u = 0; u < 8; ++u) {
        const int pA = 2 * u, pB = 2 * u + 1;
        LOADPAIR(BfB, pB);
        COMPUTEPAIR(BfA, pA);
        if (pA + 2 < 16) LOADPAIR(BfA, pA + 2);
        COMPUTEPAIR(BfB, pB);
    }

    // ---------- phase 2: cross-lane reduce + exact sequential-FMA verify ----------
    int* sc = (int*)&Xs[0];   // 128 rows x 2 halves x 16 buckets x int2 = 32 KB
    #pragma unroll
    for (int r8 = 0; r8 < 8; ++r8) {
        const int lr = 32 * wg + 16 * (r8 >> 2) + quad * 4 + (r8 & 3);
        ((int2*)sc)[(lr * 2 + half) * 16 + n] = make_int2(K1[r8], K2[r8]);
    }
    __syncthreads();

    if (tid < 128) {
        const int row  = tid;
        const int rowg = row0 + row;
        const int2* ent = (const int2*)sc + row * 32;
        int mx = (int)0x80000000;
        #pragma unroll
        for (int e2 = 0; e2 < 32; ++e2) mx = max(mx, ent[e2].x);
        const int thr = mx - BAND_INT;
        int ck[8];
        int nc = 0;
        #pragma unroll
        for (int e2 = 0; e2 < 32; ++e2) {
            const int2 kk = ent[e2];
            if (kk.x >= thr && nc < 8) ck[nc++] = ((kk.x & 63) << 4) | (e2 & 15);
            if (kk.y >= thr && nc < 8) ck[nc++] = ((kk.y & 63) << 4) | (e2 & 15);
        }
        float bd = INFINITY;
        int   bk = 0x7fffffff;
        const float4* xr = (const float4*)(x + (size_t)rowg * DIM);
        const float   aq = sAsq[row];
        for (int c = 0; c < nc; ++c) {
            const int k = ck[c];
            const float4* er = (const float4*)(emb + (size_t)k * DIM);
            float acc = 0.0f;
            #pragma unroll 4
            for (int dd = 0; dd < 32; ++dd) {   // sequential d order — matches rounds 1-5 / np
                const float4 xv = xr[dd];
                const float4 ev = er[dd];
                acc += xv.x * ev.x;
                acc += xv.y * ev.y;
                acc += xv.z * ev.z;
                acc += xv.w * ev.w;
            }
            const float t    = aq + Bsq[k];
            const float dist = t - 2.0f * acc;
            if (dist < bd || (dist == bd && k < bk)) { bd = dist; bk = k; }
        }
        sidx[row] = bk;
        atomicAdd(&counts[bk], 1);
        float ss = bd;
        #pragma unroll
        for (int off = 32; off > 0; off >>= 1) ss += __shfl_down(ss, off);
        if (lane == 0) pblk[wave] = ss;
    }
    __syncthreads();
    if (tid == 0) atomicAdd(sse, (double)(pblk[0] + pblk[1]));

    // ---------- phase 3: fused gather + STE epilogue (512 threads) ----------
    #pragma unroll
    for (int i = tid; i < 4096; i += 512) {
        const int row = i >> 5, d4 = i & 31;
        const int k = sidx[row];
        const float4 xv = *((const float4*)(x + (size_t)(row0 + row) * DIM) + d4);
        const float4 qv = *((const float4*)emb + (size_t)k * 32 + d4);
        float4 ov;
        ov.x = xv.x + (qv.x - xv.x);
        ov.y = xv.y + (qv.y - xv.y);
        ov.z = xv.z + (qv.z - xv.z);
        ov.w = xv.w + (qv.w - xv.w);
        *((float4*)out + (size_t)(row0 + row) * 32 + d4) = ov;
    }
}

// ---- loss + perplexity ----
__global__ __launch_bounds__(1024) void vq_finalize_kernel(
        const int* __restrict__ counts, const double* __restrict__ sse,
        float* __restrict__ out_tail) {
    __shared__ double red[1024];
    const int t = threadIdx.x;
    const float p = (float)counts[t] * (1.0f / 65536.0f);
    red[t] = (double)p * log((double)p + 1e-10);
    __syncthreads();
    for (int s = 512; s > 0; s >>= 1) {
        if (t < s) red[t] += red[t + s];
        __syncthreads();
    }
    if (t == 0) {
        const float m = (float)(*sse * (1.0 / 8388608.0));
        out_tail[0] = m + 0.25f * m;
        out_tail[1] = (float)exp(-red[0]);
    }
}

extern "C" void kernel_launch(void* const* d_in, const int* in_sizes, int n_in,
                              void* d_out, int out_size, void* d_ws, size_t ws_size,
                              hipStream_t stream) {
    const float* x   = (const float*)d_in[0];   // [65536 x 128]
    const float* emb = (const float*)d_in[1];   // [1024 x 128]
    float* out = (float*)d_out;

    char*           ws     = (char*)d_ws;
    float*          Bsq    = (float*)(ws + 0);
    int*            counts = (int*)(ws + 4096);
    double*         sse    = (double*)(ws + 8192);
    unsigned short* Ehi    = (unsigned short*)(ws + 16384);

    vq_prep_kernel<<<64, 256, 0, stream>>>(emb, Ehi, Bsq, counts, sse);
    vq_main_kernel<<<512, 512, 0, stream>>>(x, emb, Ehi, Bsq, counts, sse, out);
    vq_finalize_kernel<<<1, 1024, 0, stream>>>(counts, sse, out + NELEMS);
}

// Round 7
// 152.787 us; speedup vs baseline: 1.0277x; 1.0277x over previous
//
#include <hip/hip_runtime.h>
#include <cmath>

#define DIM      128
#define NELEMS   8388608
#define BAND_INT 12288   // key band >= 7.3e-4 dot units; unchanged from r4-r6 (proven)

typedef __attribute__((ext_vector_type(8))) short  short8;
typedef __attribute__((ext_vector_type(4))) float  f32x4;

// ws layout (bytes):
//   0      : float Bsq[1024]        (4096)
//   4096   : int   counts[1024]     (4096)
//   8192   : double sse             (8)
//   16384  : ushort Ehi[131072]     (262144)   -> end 278528 (<= proven 540672)

__device__ inline unsigned short f2bf(float x) {
    unsigned u = __float_as_uint(x);
    unsigned r = u + 0x7FFFu + ((u >> 16) & 1u);   // RNE; inputs finite
    return (unsigned short)(r >> 16);
}

// ---- prep: E -> bf16-hi frags [ct64][kt4][lane64][j8] + Bsq (bit-identical tree) + zero ----
__global__ __launch_bounds__(256) void vq_prep_kernel(
        const float* __restrict__ e, unsigned short* __restrict__ Ehi,
        float* __restrict__ Bsq, int* __restrict__ counts, double* __restrict__ sse) {
    const int tid = threadIdx.x;
    {
        const int t  = blockIdx.x * 256 + tid;   // 0..16383
        const int c  = t >> 4;
        const int gs = t & 15;
        const int kt = gs >> 2, qd = gs & 3;
        const int d0 = gs * 8;
        const float4 v0 = *(const float4*)(e + c * DIM + d0);
        const float4 v1 = *(const float4*)(e + c * DIM + d0 + 4);
        float f[8] = {v0.x, v0.y, v0.z, v0.w, v1.x, v1.y, v1.z, v1.w};
        unsigned short h[8];
        #pragma unroll
        for (int j = 0; j < 8; ++j) h[j] = f2bf(f[j]);
        const int ct = c >> 4, n = c & 15;
        uint4 ph;
        ph.x = h[0] | (h[1] << 16); ph.y = h[2] | (h[3] << 16);
        ph.z = h[4] | (h[5] << 16); ph.w = h[6] | (h[7] << 16);
        *(uint4*)&Ehi[(((ct * 4 + kt) * 64 + qd * 16 + n) * 8)] = ph;
    }
    // Bsq: per-row math bit-identical to round-1 rowsq (float4 squares + 32-lane xor tree)
    {
        const int lane = tid & 31;
        #pragma unroll
        for (int r2 = 0; r2 < 2; ++r2) {
            const int row = blockIdx.x * 16 + (tid >> 5) * 2 + r2;
            const float4 xv = *(const float4*)(e + (size_t)row * DIM + lane * 4);
            float s = xv.x * xv.x + xv.y * xv.y + xv.z * xv.z + xv.w * xv.w;
            #pragma unroll
            for (int off = 16; off > 0; off >>= 1) s += __shfl_xor(s, off);
            if (lane == 0) Bsq[row] = s;
        }
    }
    if (blockIdx.x == 0) {
        ((int4*)counts)[tid] = make_int4(0, 0, 0, 0);
        if (tid == 0) *sse = 0.0;
    }
}

#define LOADPAIR(BUF, P)                                                        \
    do {                                                                        \
        const unsigned short* _bp = EhiH + (size_t)(P) * 4096;                  \
        _Pragma("unroll")                                                       \
        for (int _c = 0; _c < 2; ++_c)                                          \
            _Pragma("unroll")                                                   \
            for (int _kt = 0; _kt < 4; ++_kt)                                   \
                BUF[_c][_kt] = *(const short8*)&_bp[((_c * 4 + _kt) * 64 + lane) * 8]; \
    } while (0)

#define COMPUTEPAIR(BUF, P)                                                     \
    do {                                                                        \
        _Pragma("unroll")                                                       \
        for (int _c = 0; _c < 2; ++_c) {                                        \
            const int _ct = ctbase + 2 * (P) + _c;                              \
            f32x4 _a0 = cinit, _a1 = cinit;                                     \
            _Pragma("unroll")                                                   \
            for (int _kt = 0; _kt < 4; ++_kt) {                                 \
                _a0 = __builtin_amdgcn_mfma_f32_16x16x32_bf16(Af[0][_kt], BUF[_c][_kt], _a0, 0, 0, 0); \
                _a1 = __builtin_amdgcn_mfma_f32_16x16x32_bf16(Af[1][_kt], BUF[_c][_kt], _a1, 0, 0, 0); \
            }                                                                   \
            _Pragma("unroll")                                                   \
            for (int _r = 0; _r < 4; ++_r) {                                    \
                const int _k0 = (__float_as_int(_a0[_r]) & (int)0xFFFFFFC0) | _ct; \
                const int _t0 = min(K1[_r], _k0);                               \
                K1[_r] = max(K1[_r], _k0);                                      \
                K2[_r] = max(K2[_r], _t0);                                      \
                const int _k1 = (__float_as_int(_a1[_r]) & (int)0xFFFFFFC0) | _ct; \
                const int _t1 = min(K1[4 + _r], _k1);                           \
                K1[4 + _r] = max(K1[4 + _r], _k1);                              \
                K2[4 + _r] = max(K2[4 + _r], _t1);                              \
            }                                                                   \
        }                                                                       \
    } while (0)

// ---- main: barrier-free bf16 MFMA scan + exact verify + fused epilogue ----
// 1024 blocks x 256 thr (4 waves); block = 64 rows x 1024 codes.
// Wave w: rows 32*(w&1)..+31 (2 rti), code-tiles [32*(w>>1), +32).
// Small blocks -> 4 blocks/CU resident (LDS 16KB, VGPR<=~84) = 16 waves/CU.
__global__ __launch_bounds__(256) void vq_main_kernel(
        const float* __restrict__ x, const float* __restrict__ emb,
        const unsigned short* __restrict__ Ehi, const float* __restrict__ Bsq,
        int* __restrict__ counts, double* __restrict__ sse,
        float* __restrict__ out) {
    __shared__ unsigned short Xs[8192];   // 16 KB: A-frags [rg4][kt4][lane64][j8]; reused as sc
    __shared__ float sAsq[64];
    __shared__ int   sidx[64];

    const int tid  = threadIdx.x;
    const int wave = tid >> 6;
    const int lane = tid & 63;
    const int n    = lane & 15;
    const int quad = lane >> 4;
    const int wg   = wave & 1;        // row-group: rows 32*wg .. 32*wg+31
    const int half = wave >> 1;       // code half: cts [32*half, 32*half+32)
    const int ctbase = half * 32;
    const int row0 = blockIdx.x * 64;

    // ---------- phase 0: stage A-hi frags + bit-exact Asq (round-1 xor tree) ----------
    {
        const int rl = tid >> 3, tq = tid & 7;   // rl 0..31, 8 threads/row
        const int dbase = tq * 16;
        #pragma unroll
        for (int w = 0; w < 2; ++w) {
            const int r  = 32 * w + rl;
            const int rg = r >> 4, m = r & 15;
            const float* xp = x + (size_t)(row0 + r) * DIM + dbase;
            float p[4];
            #pragma unroll
            for (int q = 0; q < 4; ++q) {
                const float4 v = *(const float4*)(xp + 4 * q);
                p[q] = v.x * v.x + v.y * v.y + v.z * v.z + v.w * v.w;
                const int dd = dbase + 4 * q;
                const int kt = dd >> 5, qd = (dd >> 3) & 3, j = dd & 7;
                unsigned short h0 = f2bf(v.x), h1 = f2bf(v.y), h2 = f2bf(v.z), h3 = f2bf(v.w);
                uint2 ph;
                ph.x = h0 | (h1 << 16); ph.y = h2 | (h3 << 16);
                *(uint2*)&Xs[(((rg * 4 + kt) * 64 + qd * 16 + m) * 8) + j] = ph;
            }
            // xor-tree: levels 16,8,4 cross-thread (tq bits), 2,1 intra — bit-exact vs round 1
            #pragma unroll
            for (int q = 0; q < 4; ++q) p[q] += __shfl_xor(p[q], 4);
            #pragma unroll
            for (int q = 0; q < 4; ++q) p[q] += __shfl_xor(p[q], 2);
            #pragma unroll
            for (int q = 0; q < 4; ++q) p[q] += __shfl_xor(p[q], 1);
            const float s = (p[0] + p[2]) + (p[1] + p[3]);
            if (tq == 0) sAsq[r] = s;
        }
    }
    __syncthreads();

    short8 Af[2][4];
    #pragma unroll
    for (int rti = 0; rti < 2; ++rti)
        #pragma unroll
        for (int kt = 0; kt < 4; ++kt)
            Af[rti][kt] = *(const short8*)&Xs[(((wg * 2 + rti) * 4 + kt) * 64 + lane) * 8];
    __syncthreads();   // all frag reads done before Xs is reused as scratch

    // ---------- phase 1: barrier-free scan over this wave's 16 ct-pairs ----------
    int K1[8], K2[8];
    #pragma unroll
    for (int i = 0; i < 8; ++i) { K1[i] = (int)0x80000000; K2[i] = (int)0x80000000; }

    const f32x4 cinit = {1.0f, 1.0f, 1.0f, 1.0f};   // +1.0 bias -> positive, int-monotone keys
    const unsigned short* EhiH = Ehi + (size_t)half * 65536;   // 16 pairs x 4096 shorts

    short8 BfA[2][4], BfB[2][4];
    LOADPAIR(BfA, 0);
    for (int u = 0; u < 8; ++u) {
        const int pA = 2 * u, pB = 2 * u + 1;
        LOADPAIR(BfB, pB);
        COMPUTEPAIR(BfA, pA);
        if (pA + 2 < 16) LOADPAIR(BfA, pA + 2);
        COMPUTEPAIR(BfB, pB);
    }

    // ---------- phase 2: cross-lane reduce + exact sequential-FMA verify ----------
    int* sc = (int*)&Xs[0];   // 64 rows x 2 halves x 16 buckets x int2 = 16 KB
    #pragma unroll
    for (int r8 = 0; r8 < 8; ++r8) {
        const int lr = 32 * wg + 16 * (r8 >> 2) + quad * 4 + (r8 & 3);
        ((int2*)sc)[(lr * 2 + half) * 16 + n] = make_int2(K1[r8], K2[r8]);
    }
    __syncthreads();

    if (tid < 64) {
        const int row  = tid;
        const int rowg = row0 + row;
        const int2* ent = (const int2*)sc + row * 32;
        int mx = (int)0x80000000;
        #pragma unroll
        for (int e2 = 0; e2 < 32; ++e2) mx = max(mx, ent[e2].x);
        const int thr = mx - BAND_INT;
        int ck[8];
        int nc = 0;
        #pragma unroll
        for (int e2 = 0; e2 < 32; ++e2) {
            const int2 kk = ent[e2];
            if (kk.x >= thr && nc < 8) ck[nc++] = ((kk.x & 63) << 4) | (e2 & 15);
            if (kk.y >= thr && nc < 8) ck[nc++] = ((kk.y & 63) << 4) | (e2 & 15);
        }
        float bd = INFINITY;
        int   bk = 0x7fffffff;
        const float4* xr = (const float4*)(x + (size_t)rowg * DIM);
        const float   aq = sAsq[row];
        for (int c = 0; c < nc; ++c) {
            const int k = ck[c];
            const float4* er = (const float4*)(emb + (size_t)k * DIM);
            float acc = 0.0f;
            #pragma unroll 4
            for (int dd = 0; dd < 32; ++dd) {   // sequential d order — matches rounds 1-6 / np
                const float4 xv = xr[dd];
                const float4 ev = er[dd];
                acc += xv.x * ev.x;
                acc += xv.y * ev.y;
                acc += xv.z * ev.z;
                acc += xv.w * ev.w;
            }
            const float t    = aq + Bsq[k];
            const float dist = t - 2.0f * acc;
            if (dist < bd || (dist == bd && k < bk)) { bd = dist; bk = k; }
        }
        sidx[row] = bk;
        atomicAdd(&counts[bk], 1);
        float ss = bd;   // tid<64 is exactly wave 0 -> wave-level reduce + 1 atomic
        #pragma unroll
        for (int off = 32; off > 0; off >>= 1) ss += __shfl_down(ss, off);
        if (tid == 0) atomicAdd(sse, (double)ss);
    }
    __syncthreads();

    // ---------- phase 3: fused gather + STE epilogue ----------
    #pragma unroll
    for (int i = tid; i < 2048; i += 256) {
        const int row = i >> 5, d4 = i & 31;
        const int k = sidx[row];
        const float4 xv = *((const float4*)(x + (size_t)(row0 + row) * DIM) + d4);
        const float4 qv = *((const float4*)emb + (size_t)k * 32 + d4);
        float4 ov;
        ov.x = xv.x + (qv.x - xv.x);
        ov.y = xv.y + (qv.y - xv.y);
        ov.z = xv.z + (qv.z - xv.z);
        ov.w = xv.w + (qv.w - xv.w);
        *((float4*)out + (size_t)(row0 + row) * 32 + d4) = ov;
    }
}

// ---- loss + perplexity ----
__global__ __launch_bounds__(1024) void vq_finalize_kernel(
        const int* __restrict__ counts, const double* __restrict__ sse,
        float* __restrict__ out_tail) {
    __shared__ double red[1024];
    const int t = threadIdx.x;
    const float p = (float)counts[t] * (1.0f / 65536.0f);
    red[t] = (double)p * log((double)p + 1e-10);
    __syncthreads();
    for (int s = 512; s > 0; s >>= 1) {
        if (t < s) red[t] += red[t + s];
        __syncthreads();
    }
    if (t == 0) {
        const float m = (float)(*sse * (1.0 / 8388608.0));
        out_tail[0] = m + 0.25f * m;
        out_tail[1] = (float)exp(-red[0]);
    }
}

extern "C" void kernel_launch(void* const* d_in, const int* in_sizes, int n_in,
                              void* d_out, int out_size, void* d_ws, size_t ws_size,
                              hipStream_t stream) {
    const float* x   = (const float*)d_in[0];   // [65536 x 128]
    const float* emb = (const float*)d_in[1];   // [1024 x 128]
    float* out = (float*)d_out;

    char*           ws     = (char*)d_ws;
    float*          Bsq    = (float*)(ws + 0);
    int*            counts = (int*)(ws + 4096);
    double*         sse    = (double*)(ws + 8192);
    unsigned short* Ehi    = (unsigned short*)(ws + 16384);

    vq_prep_kernel<<<64, 256, 0, stream>>>(emb, Ehi, Bsq, counts, sse);
    vq_main_kernel<<<1024, 256, 0, stream>>>(x, emb, Ehi, Bsq, counts, sse, out);
    vq_finalize_kernel<<<1, 1024, 0, stream>>>(counts, sse, out + NELEMS);
}